// Round 1
// 524.554 us; speedup vs baseline: 1.1420x; 1.1420x over previous
//
#include <hip/hip_runtime.h>

#define BATCH 8
#define PN    16384
#define NSAMP 256
#define KDIM  512
#define HID   384
#define HALF  192
#define CIN   576   // HID + HALF
#define ROWS  2048  // BATCH * NSAMP
#define BN_EPS 1e-5f

// workspace offsets (in floats)
#define OFF_GF   0
#define OFF_W1T  3072
#define OFF_W2T  224256
#define OFF_IDX  371712   /* 2048 ints */
#define OFF_H1   373760
#define OFF_H2   1160192
#define OFF_SUM1 1946624
#define OFF_SQ1  1947008
#define OFF_SUM2 1947392
#define OFF_SQ2  1947776

typedef float v2f __attribute__((ext_vector_type(2)));

// ---- K1: fused FPS (blocks 0..7) + prep (blocks 8..32) --------------------
// FPS on 192-dim local_feat == FPS on 3-dim p under metric G = Wc Wc^T = LL^T.
// d(i,j) = ||L^T p_i - L^T p_j||^2 ; q = L^T p precomputed per point.
// Distance math identical to the passing version (fmaf chain, fmin update).
// Argmax restructured: value-only f32 reduction (v_max3 trees + f32 butterfly)
// + rare "claim" phase (exact-equality scan + LDS atomicMin of global index)
// which reproduces the first-index tie-break of jnp.argmax exactly.
__global__ __launch_bounds__(1024) void k_main(const float* p, const float* Wc,
                                               const float* pf, const float* Wf,
                                               const float* bfe, const float* W1,
                                               const float* W2, float* ws) {
  __shared__ float s[KDIM];
  __shared__ float Msh[6];
  __shared__ __align__(16) float redv[2][16];
  __shared__ int widx[2];
  int blk = blockIdx.x, t = threadIdx.x;

  if (blk >= 8) {                    // ---- prep work, hidden under FPS ----
    if (blk < 16) {                  // W1t[c][o] = W1[o][c]
      for (int sI = (blk - 8) * 1024 + t; sI < HID * CIN; sI += 8192) {
        int o = sI / CIN, c = sI % CIN;
        ws[OFF_W1T + c * HID + o] = W1[sI];
      }
    } else if (blk < 24) {           // W2t[c][o] = W2[o][c]
      for (int sI = (blk - 16) * 1024 + t; sI < HID * HID; sI += 8192) {
        int o = sI / HID, c = sI % HID;
        ws[OFF_W2T + c * HID + o] = W2[sI];
      }
    } else if (blk < 32) {           // global_feat[b] = pf[b] @ W_feat + b_feat
      int b = blk - 24;
      if (t < KDIM) s[t] = pf[b * KDIM + t];
      __syncthreads();
      if (t < HID) {
        float acc = bfe[t];
        for (int k = 0; k < KDIM; k++) acc = fmaf(s[k], Wf[k * HID + t], acc);
        ws[OFF_GF + b * HID + t] = acc;
      }
    } else {                         // zero BN sums (contiguous 1536 floats)
      for (int i = t; i < 1536; i += 1024) ws[OFF_SUM1 + i] = 0.f;
    }
    return;
  }

  // ---- FPS, one batch per block ----
  int b = blk;
  int* idx_out = (int*)(ws + OFF_IDX);

  if (t < 64) {                      // G (3x3) in fp64 + Cholesky, wave 0
    double g0 = 0, g1 = 0, g2 = 0, g3 = 0, g4 = 0, g5 = 0;
    for (int k = t; k < HALF; k += 64) {
      double w0 = (double)Wc[k];
      double w1 = (double)Wc[HALF + k];
      double w2 = (double)Wc[2 * HALF + k];
      g0 += w0 * w0; g1 += w0 * w1; g2 += w0 * w2;
      g3 += w1 * w1; g4 += w1 * w2; g5 += w2 * w2;
    }
    for (int off = 32; off; off >>= 1) {
      g0 += __shfl_down(g0, off, 64); g1 += __shfl_down(g1, off, 64);
      g2 += __shfl_down(g2, off, 64); g3 += __shfl_down(g3, off, 64);
      g4 += __shfl_down(g4, off, 64); g5 += __shfl_down(g5, off, 64);
    }
    if (t == 0) {
      double l00 = sqrt(g0);
      double l10 = g1 / l00, l20 = g2 / l00;
      double l11 = sqrt(g3 - l10 * l10);
      double l21 = (g4 - l10 * l20) / l11;
      double l22 = sqrt(g5 - l20 * l20 - l21 * l21);
      Msh[0] = (float)l00; Msh[1] = (float)l10; Msh[2] = (float)l20;
      Msh[3] = (float)l11; Msh[4] = (float)l21; Msh[5] = (float)l22;
    }
  }
  __syncthreads();
  float m00 = Msh[0], m10 = Msh[1], m20 = Msh[2];
  float m11 = Msh[3], m21 = Msh[4], m22 = Msh[5];

  const float* pb = p + b * PN * 3;
  // ownership: pair jj holds global points i0=(2*jj)*1024+t and i1=i0+1024
  v2f qx[8], qy[8], qz[8], dist[8];
#pragma unroll
  for (int j = 0; j < 8; j++) {
    int i0 = ((2 * j) << 10) + t;
    int i1 = i0 + 1024;
    float x0 = pb[i0 * 3], y0 = pb[i0 * 3 + 1], z0 = pb[i0 * 3 + 2];
    float x1 = pb[i1 * 3], y1 = pb[i1 * 3 + 1], z1 = pb[i1 * 3 + 2];
    qx[j] = (v2f){fmaf(m00, x0, fmaf(m10, y0, m20 * z0)),
                  fmaf(m00, x1, fmaf(m10, y1, m20 * z1))};
    qy[j] = (v2f){fmaf(m11, y0, m21 * z0), fmaf(m11, y1, m21 * z1)};
    qz[j] = (v2f){m22 * z0, m22 * z1};
    dist[j] = (v2f){1e10f, 1e10f};
  }

  int far = 0, par = 0;
  for (int k = 0; k < NSAMP; k++) {
    if (t == 0) {
      idx_out[b * NSAMP + k] = far;  // scan emits pre-update far
      widx[par] = 0x7fffffff;        // reset claim slot (read 2 steps ago)
    }
    float x = pb[far * 3], y = pb[far * 3 + 1], z = pb[far * 3 + 2];
    float cx = fmaf(m00, x, fmaf(m10, y, m20 * z));
    float cy = fmaf(m11, y, m21 * z);
    float cz = m22 * z;
    v2f cxv = (v2f){cx, cx}, cyv = (v2f){cy, cy}, czv = (v2f){cz, cz};
#pragma unroll
    for (int j = 0; j < 8; j++) {    // packed distance update (v_pk_fma_f32)
      v2f dx = qx[j] - cxv, dy = qy[j] - cyv, dz = qz[j] - czv;
      v2f d = __builtin_elementwise_fma(
          dx, dx, __builtin_elementwise_fma(dy, dy, dz * dz));
      dist[j] = __builtin_elementwise_min(dist[j], d);
    }
    // per-thread max of 16 (v_max3 tree)
    float a0 = fmaxf(dist[0].x, dist[0].y);
    float a1 = fmaxf(dist[1].x, dist[1].y);
    float a2 = fmaxf(dist[2].x, dist[2].y);
    float a3 = fmaxf(dist[3].x, dist[3].y);
    float a4 = fmaxf(dist[4].x, dist[4].y);
    float a5 = fmaxf(dist[5].x, dist[5].y);
    float a6 = fmaxf(dist[6].x, dist[6].y);
    float a7 = fmaxf(dist[7].x, dist[7].y);
    float b0 = fmaxf(fmaxf(a0, a1), a2);
    float b1 = fmaxf(fmaxf(a3, a4), a5);
    float tmax = fmaxf(fmaxf(b0, b1), fmaxf(a6, a7));
    // wave butterfly (f32), then one slot per wave
    float m = tmax;
#pragma unroll
    for (int off = 32; off; off >>= 1) m = fmaxf(m, __shfl_xor(m, off, 64));
    if ((t & 63) == 0) redv[par][t >> 6] = m;
    __syncthreads();
    float4 r0 = *(const float4*)&redv[par][0];
    float4 r1 = *(const float4*)&redv[par][4];
    float4 r2 = *(const float4*)&redv[par][8];
    float4 r3 = *(const float4*)&redv[par][12];
    float g01 = fmaxf(fmaxf(r0.x, r0.y), r0.z);
    float g02 = fmaxf(fmaxf(r0.w, r1.x), r1.y);
    float g03 = fmaxf(fmaxf(r1.z, r1.w), r2.x);
    float g04 = fmaxf(fmaxf(r2.y, r2.z), r2.w);
    float g05 = fmaxf(fmaxf(r3.x, r3.y), r3.z);
    float gmax = fmaxf(fmaxf(fmaxf(g01, g02), g03),
                       fmaxf(fmaxf(g04, g05), r3.w));
    if (tmax == gmax) {              // rare claim: exact-equality index scan
      int mi = 0x7fffffff;
#pragma unroll
      for (int j = 0; j < 8; j++) {
        if (dist[j].x == gmax) mi = min(mi, ((2 * j) << 10) + t);
        if (dist[j].y == gmax) mi = min(mi, ((2 * j + 1) << 10) + t);
      }
      atomicMin(&widx[par], mi);     // smallest global index wins => argmax
    }
    __syncthreads();
    far = widx[par];
    par ^= 1;                        // double-buffer the claim slot
  }
}

// ---- K2: GEMM1 (fused gather of combined) + bias + BN1 sums --------------
__global__ __launch_bounds__(384) void k_gemm1(const float* p,
                                               const float* Wc,
                                               const float* bc,
                                               const float* b1,
                                               float* ws) {
  __shared__ __align__(16) float ct[CIN * 8];
  int t = threadIdx.x;
  int row0 = blockIdx.x * 8;
  const int* fidx = (const int*)(ws + OFF_IDX);
  for (int sI = t; sI < 8 * CIN; sI += 384) {  // stage tile transposed ct[c*8+r]
    int r = sI / CIN, c = sI % CIN;
    int row = row0 + r, b = row >> 8;
    float val;
    if (c < HID) {
      val = ws[OFF_GF + b * HID + c];          // broadcast global_feat
    } else {
      int co = c - HID;
      int i = fidx[row];
      const float* pp = p + (b * PN + i) * 3;
      val = bc[co];
      val = fmaf(pp[0], Wc[co], val);
      val = fmaf(pp[1], Wc[HALF + co], val);
      val = fmaf(pp[2], Wc[2 * HALF + co], val);  // sampled local_feat
    }
    ct[c * 8 + r] = val;
  }
  __syncthreads();
  const float* w1t = ws + OFF_W1T;
  float acc[8] = {0.f, 0.f, 0.f, 0.f, 0.f, 0.f, 0.f, 0.f};
  for (int c = 0; c < CIN; c++) {
    float w = w1t[c * HID + t];
    float4 a0 = *(const float4*)(ct + c * 8);
    float4 a1 = *(const float4*)(ct + c * 8 + 4);
    acc[0] = fmaf(a0.x, w, acc[0]); acc[1] = fmaf(a0.y, w, acc[1]);
    acc[2] = fmaf(a0.z, w, acc[2]); acc[3] = fmaf(a0.w, w, acc[3]);
    acc[4] = fmaf(a1.x, w, acc[4]); acc[5] = fmaf(a1.y, w, acc[5]);
    acc[6] = fmaf(a1.z, w, acc[6]); acc[7] = fmaf(a1.w, w, acc[7]);
  }
  float bias = b1[t];
  float sv = 0.f, sq = 0.f;
#pragma unroll
  for (int r = 0; r < 8; r++) {
    float v = acc[r] + bias;
    ws[OFF_H1 + (row0 + r) * HID + t] = v;
    sv += v; sq = fmaf(v, v, sq);
  }
  atomicAdd(&ws[OFF_SUM1 + t], sv);
  atomicAdd(&ws[OFF_SQ1 + t], sq);
}

// ---- K3: GEMM2 with inline BN1 finalize + ReLU on load -------------------
__global__ __launch_bounds__(384) void k_gemm2(const float* b2,
                                               const float* g1,
                                               const float* be1,
                                               float* ws) {
  __shared__ __align__(16) float ht[HID * 8];
  __shared__ float sc1s[HID], sh1s[HID];
  int t = threadIdx.x;
  int row0 = blockIdx.x * 8;
  {                                   // BN1 finalize, redundantly per block
    float m = ws[OFF_SUM1 + t] * (1.f / ROWS);
    float v = ws[OFF_SQ1 + t] * (1.f / ROWS) - m * m;
    float inv = 1.f / sqrtf(v + BN_EPS);
    float sc = inv * g1[t];
    sc1s[t] = sc;
    sh1s[t] = be1[t] - m * sc;
  }
  __syncthreads();
  for (int sI = t; sI < 8 * HID; sI += 384) {
    int r = sI / HID, c = sI % HID;
    float x = fmaf(ws[OFF_H1 + (row0 + r) * HID + c], sc1s[c], sh1s[c]);
    ht[c * 8 + r] = fmaxf(x, 0.f);
  }
  __syncthreads();
  const float* w2t = ws + OFF_W2T;
  float acc[8] = {0.f, 0.f, 0.f, 0.f, 0.f, 0.f, 0.f, 0.f};
  for (int c = 0; c < HID; c++) {
    float w = w2t[c * HID + t];
    float4 a0 = *(const float4*)(ht + c * 8);
    float4 a1 = *(const float4*)(ht + c * 8 + 4);
    acc[0] = fmaf(a0.x, w, acc[0]); acc[1] = fmaf(a0.y, w, acc[1]);
    acc[2] = fmaf(a0.z, w, acc[2]); acc[3] = fmaf(a0.w, w, acc[3]);
    acc[4] = fmaf(a1.x, w, acc[4]); acc[5] = fmaf(a1.y, w, acc[5]);
    acc[6] = fmaf(a1.z, w, acc[6]); acc[7] = fmaf(a1.w, w, acc[7]);
  }
  float bias = b2[t];
  float sv = 0.f, sq = 0.f;
#pragma unroll
  for (int r = 0; r < 8; r++) {
    float v = acc[r] + bias;
    ws[OFF_H2 + (row0 + r) * HID + t] = v;
    sv += v; sq = fmaf(v, v, sq);
  }
  atomicAdd(&ws[OFF_SUM2 + t], sv);
  atomicAdd(&ws[OFF_SQ2 + t], sq);
}

// ---- K4: inline BN2 finalize + affine + ReLU -----------------------------
__global__ __launch_bounds__(256) void k_out(const float* ws, const float* g2,
                                             const float* be2, float* out) {
  int gid = blockIdx.x * 256 + threadIdx.x;
  int i = gid * 4;
  int c = i % HID;                    // multiple of 4
  float4 h  = *(const float4*)(ws + OFF_H2 + i);
  float4 s2 = *(const float4*)(ws + OFF_SUM2 + c);
  float4 q2 = *(const float4*)(ws + OFF_SQ2 + c);
  float4 gv = *(const float4*)(g2 + c);
  float4 bv = *(const float4*)(be2 + c);
  float4 r;
#define BN2(comp) {                                                  \
    float m  = s2.comp * (1.f / ROWS);                               \
    float v  = q2.comp * (1.f / ROWS) - m * m;                       \
    float sc = (1.f / sqrtf(v + BN_EPS)) * gv.comp;                  \
    float sh = bv.comp - m * sc;                                     \
    r.comp = fmaxf(fmaf(h.comp, sc, sh), 0.f); }
  BN2(x) BN2(y) BN2(z) BN2(w)
#undef BN2
  ((float4*)out)[gid] = r;
}

extern "C" void kernel_launch(void* const* d_in, const int* in_sizes, int n_in,
                              void* d_out, int out_size, void* d_ws, size_t ws_size,
                              hipStream_t stream) {
  const float* p   = (const float*)d_in[0];
  // d_in[1] = N (int scalar, always 256)
  const float* pf  = (const float*)d_in[2];
  const float* Wf  = (const float*)d_in[3];
  const float* bfe = (const float*)d_in[4];
  const float* Wc  = (const float*)d_in[5];
  const float* bc  = (const float*)d_in[6];
  const float* W1  = (const float*)d_in[7];
  const float* b1  = (const float*)d_in[8];
  const float* g1  = (const float*)d_in[9];
  const float* be1 = (const float*)d_in[10];
  const float* W2  = (const float*)d_in[11];
  const float* b2  = (const float*)d_in[12];
  const float* g2  = (const float*)d_in[13];
  const float* be2 = (const float*)d_in[14];
  float* ws = (float*)d_ws;

  hipLaunchKernelGGL(k_main,  dim3(33),  dim3(1024), 0, stream,
                     p, Wc, pf, Wf, bfe, W1, W2, ws);
  hipLaunchKernelGGL(k_gemm1, dim3(256), dim3(384), 0, stream, p, Wc, bc, b1, ws);
  hipLaunchKernelGGL(k_gemm2, dim3(256), dim3(384), 0, stream, b2, g1, be1, ws);
  hipLaunchKernelGGL(k_out,   dim3(768), dim3(256), 0, stream,
                     ws, g2, be2, (float*)d_out);
}